// Round 15
// baseline (64.023 us; speedup 1.0000x reference)
//
#include <hip/hip_runtime.h>
#include <hip/hip_bf16.h>
#include <stdint.h>

#define XLEN   262144
#define NT     513
#define NTP    528               // padded frames per batch (8*528 = 4224)
#define NB     8
#define NCOL   (NB * NTP)        // 4224 fused columns
#define NFFT   2048
#define OUTKT  (2048 * NT)

// radix-8 geometry
#define NKC8   192               // padded computed k rows (valid 0..128), 3 tiles
#define KO     256               // eighth transform length
#define WSTR8  ((size_t)NKC8 * KO)    // 49,152 shorts per weight mat
#define FSTR8  ((size_t)NCOL * KO)    // 1,081,344 shorts per frame mat
#define PSTR8  ((size_t)NKC8 * NCOL)  // 811,008 elements per partial (bf16)

// radix-4 fallback geometry
#define NKC4   320
#define KQ     512
#define WSTR   ((size_t)NKC4 * KQ)
#define FSTR   ((size_t)NCOL * KQ)
#define PSTR   ((size_t)NKC4 * NCOL)

typedef __attribute__((ext_vector_type(8))) short short8;
typedef __attribute__((ext_vector_type(4))) short short4v;
typedef __attribute__((ext_vector_type(2))) short short2v;
typedef __attribute__((ext_vector_type(4))) float f32x4;

__device__ __forceinline__ short cvt_bf16(float f) {
  return __builtin_bit_cast(short, (__bf16)f);
}

__device__ __forceinline__ f32x4 bf4_to_f32(short4v v) {
  f32x4 o;
#pragma unroll
  for (int e = 0; e < 4; ++e) {
    uint32_t u = ((uint32_t)(uint16_t)v[e]) << 16;
    o[e] = __builtin_bit_cast(float, u);
  }
  return o;
}

__device__ __forceinline__ void gload16(const short* g, const short* l) {
  __builtin_amdgcn_global_load_lds(
      (const __attribute__((address_space(1))) void*)g,
      (__attribute__((address_space(3))) void*)l, 16, 0, 0);
}

// ==================== radix-8 path ====================

// ---- prep: weights rows 0..128 split by n mod 8 -> 16 bf16 mats [192][256] ----
__global__ __launch_bounds__(256) void conv_w_split8(
    const float* __restrict__ wsin, const float* __restrict__ wcos,
    short* __restrict__ wc8, short* __restrict__ ws8) {
  const int row = blockIdx.x;           // 0..191
  const int m = threadIdx.x;            // 0..255
  const int n0 = m * 8;
  short c[8], s[8];
  if (row <= 128) {
    const float* pc = wcos + (size_t)row * NFFT + n0;
    const float* ps = wsin + (size_t)row * NFFT + n0;
    f32x4 c0 = *(const f32x4*)pc, c1 = *(const f32x4*)(pc + 4);
    f32x4 s0 = *(const f32x4*)ps, s1 = *(const f32x4*)(ps + 4);
#pragma unroll
    for (int r = 0; r < 4; ++r) {
      c[r] = cvt_bf16(c0[r]); c[4 + r] = cvt_bf16(c1[r]);
      s[r] = cvt_bf16(s0[r]); s[4 + r] = cvt_bf16(s1[r]);
    }
  } else {
#pragma unroll
    for (int r = 0; r < 8; ++r) { c[r] = 0; s[r] = 0; }
  }
  const size_t o = (size_t)row * KO + m;
#pragma unroll
  for (int r = 0; r < 8; ++r) {
    wc8[r * WSTR8 + o] = c[r];
    ws8[r * WSTR8 + o] = s[r];
  }
}

// ---- prep: reflect-padded frames split by n mod 8 -> 8 bf16 mats [4224][256] ----
__global__ __launch_bounds__(256) void conv_fr_split8(const float* __restrict__ x,
                                                      short* __restrict__ fr8) {
  const int j = blockIdx.x;
  const int b = j / NTP;
  const int t = j - b * NTP;
  const int m = threadIdx.x;
  short v[8];
  if (t < NT) {
    const float* xb = x + (size_t)b * XLEN;
    const int q0 = t * 512 + m * 8 - 1024;
    float f[8];
    if (q0 >= 0 && q0 + 7 < XLEN) {
      *(f32x4*)(f)     = *(const f32x4*)(xb + q0);
      *(f32x4*)(f + 4) = *(const f32x4*)(xb + q0 + 4);
    } else {
#pragma unroll
      for (int e = 0; e < 8; ++e) {
        int mm = q0 + e;
        mm = (mm < 0) ? -mm : mm;
        mm = (mm >= XLEN) ? (2 * XLEN - 2 - mm) : mm;
        f[e] = xb[mm];
      }
    }
#pragma unroll
    for (int r = 0; r < 8; ++r) v[r] = cvt_bf16(f[r]);
  } else {
#pragma unroll
    for (int r = 0; r < 8; ++r) v[r] = 0;
  }
  const size_t o = (size_t)j * KO + m;
#pragma unroll
  for (int r = 0; r < 8; ++r) fr8[r * FSTR8 + o] = v[r];
}

// ---- split GEMM: proven structure, K=256, one residue side per block ----
// BM=64, BN=128, BK=64; 4 waves 2x2, each 32x64 per matrix; per substep
// 8 ds_read_b128 : 16 MFMA. LDS single 32 KiB, (row&7) 16B-chunk XOR swizzle
// on global source + ds_read (rule #21). bf16 partial write.
__global__ __launch_bounds__(256, 4) void dft_gemm_split8(
    const short* __restrict__ wc8, const short* __restrict__ ws8,
    const short* __restrict__ fr8,
    short* __restrict__ pC8, short* __restrict__ pS8) {
  __shared__ short lds[16384];  // 32 KiB

  const int tid  = threadIdx.x;
  const int lane = tid & 63;
  const int wid  = tid >> 6;

  // bijective XCD swizzle: nwg=792=8*99 -> even split; each XCD ~ one side
  // (side frame mat = 2.16 MB, fits 4 MB per-XCD L2).
  const int o   = blockIdx.x;
  const int xcd = o & 7;
  const int wg  = xcd * 99 + (o >> 3);
  const int side = wg / 99;         // residue r = 0..7
  const int w    = wg - side * 99;
  const int k0   = (w % 3) * 64;
  const int j0   = (w / 3) * 128;

  const short* Ac = wc8 + side * WSTR8;
  const short* As = ws8 + side * WSTR8;
  const short* Bf = fr8 + side * FSTR8;
  short* pC = pC8 + side * PSTR8;
  short* pS = pS8 + side * PSTR8;

  const int wrow = (wid >> 1) * 32;
  const int wcol = (wid & 1) * 64;

  f32x4 accC[2][4], accS[2][4];
#pragma unroll
  for (int m = 0; m < 2; ++m)
#pragma unroll
    for (int n = 0; n < 4; ++n) { accC[m][n] = (f32x4)0.0f; accS[m][n] = (f32x4)0.0f; }

  const int fr_r = lane & 15;
  const int srow = lane >> 3;
  const int scol = ((lane & 7) ^ srow) * 8;

  // buffer = 32 chunks of (8 rows x 64 shorts); 8 per wave
  auto stage = [&](int n0) {
#pragma unroll
    for (int i2 = 0; i2 < 8; ++i2) {
      const int q = wid * 8 + i2;  // wave-uniform
      const short* src;
      int dst;
      if (q < 8) {
        src = Ac + (size_t)(k0 + q * 8 + srow) * KO + n0 + scol;
        dst = q * 512;
      } else if (q < 16) {
        src = As + (size_t)(k0 + (q - 8) * 8 + srow) * KO + n0 + scol;
        dst = 4096 + (q - 8) * 512;
      } else {
        src = Bf + (size_t)(j0 + (q - 16) * 8 + srow) * KO + n0 + scol;
        dst = 8192 + (q - 16) * 512;
      }
      gload16(src, &lds[dst]);
    }
  };

  for (int ts = 0; ts < 4; ++ts) {
    if (ts) __syncthreads();
    stage(ts * 64);
    __syncthreads();
#pragma unroll
    for (int ks = 0; ks < 2; ++ks) {
      const int cc = ks * 4 + (lane >> 4);
      short8 aC[2], aS[2], bF[4];
#pragma unroll
      for (int m = 0; m < 2; ++m) {
        const int r = wrow + m * 16 + fr_r;
        const int off = (r << 6) + ((cc ^ (r & 7)) << 3);
        aC[m] = *(const short8*)&lds[off];
        aS[m] = *(const short8*)&lds[4096 + off];
      }
#pragma unroll
      for (int n = 0; n < 4; ++n) {
        const int r = wcol + n * 16 + fr_r;
        const int off = (r << 6) + ((cc ^ (r & 7)) << 3);
        bF[n] = *(const short8*)&lds[8192 + off];
      }
#pragma unroll
      for (int m = 0; m < 2; ++m)
#pragma unroll
        for (int n = 0; n < 4; ++n) {
          accC[m][n] = __builtin_amdgcn_mfma_f32_16x16x32_bf16(aC[m], bF[n], accC[m][n], 0, 0, 0);
          accS[m][n] = __builtin_amdgcn_mfma_f32_16x16x32_bf16(aS[m], bF[n], accS[m][n], 0, 0, 0);
        }
    }
  }

  // epilogue: bf16 partial write
#pragma unroll
  for (int m = 0; m < 2; ++m) {
    const int row = k0 + wrow + m * 16 + (lane >> 4) * 4;
#pragma unroll
    for (int n = 0; n < 4; ++n) {
      const int col = j0 + wcol + n * 16 + (lane & 15);
      const size_t base = (size_t)row * NCOL + col;
#pragma unroll
      for (int r = 0; r < 4; ++r) {
        pC[base + (size_t)r * NCOL] = cvt_bf16(accC[m][n][r]);
        pS[base + (size_t)r * NCOL] = cvt_bf16(accS[m][n][r]);
      }
    }
  }
}

// ---- combine: radix-8 butterfly + Hermitian mirrors ----
// C_{256j+k} = sum_r CT[jr&7]*Cr - ST[jr&7]*Sr ; S likewise (ST*Cr + CT*Sr).
// Direct rows d = 256j + k (k in [0,128]); mirror 2048-d = 256*(8-j) - k for
// k in [1,127]. outR=C, outI=-S; mirrors outI=+S. (Formula validated by
// re-deriving the passing radix-4 coefficients at j in {0..3}, r stride 2.)
__global__ __launch_bounds__(256) void combine8_kernel(
    const short* __restrict__ pC8, const short* __restrict__ pS8,
    float* __restrict__ outR, float* __restrict__ outI) {
  const int k  = blockIdx.y;                       // 0..128
  const int jq = blockIdx.x * 256 + threadIdx.x;   // quad index
  if (jq >= NCOL / 4) return;
  const int j = jq * 4;
  const int b = j / NTP;
  const int t = j - b * NTP;                       // NTP%4==0 -> same b for all 4
  const size_t pb = (size_t)k * NCOL + j;
  f32x4 C[8], S[8];
#pragma unroll
  for (int r = 0; r < 8; ++r) {
    C[r] = bf4_to_f32(*(const short4v*)&pC8[r * PSTR8 + pb]);
    S[r] = bf4_to_f32(*(const short4v*)&pS8[r * PSTR8 + pb]);
  }
  const float RT2 = 0.70710678118654752f;
  const float CT[8] = {1.f, RT2, 0.f, -RT2, -1.f, -RT2, 0.f, RT2};
  const float ST[8] = {0.f, RT2, 1.f, RT2, 0.f, -RT2, -1.f, -RT2};

  const size_t ob = (size_t)b * OUTKT + t;
  const bool mir = (k >= 1) && (k <= 127);
#pragma unroll
  for (int jj = 0; jj < 8; ++jj) {
    f32x4 Cw = (f32x4)0.0f, Sw = (f32x4)0.0f;
#pragma unroll
    for (int r = 0; r < 8; ++r) {
      const float ct = CT[(jj * r) & 7];
      const float st = ST[(jj * r) & 7];
      Cw += ct * C[r] - st * S[r];
      Sw += st * C[r] + ct * S[r];
    }
    const int rowD = 256 * jj + k;
    float* rD = outR + ob + (size_t)rowD * NT;
    float* iD = outI + ob + (size_t)rowD * NT;
    const int rowM = 256 * (8 - jj) - k;
    float* rM = outR + ob + (size_t)rowM * NT;
    float* iM = outI + ob + (size_t)rowM * NT;
#pragma unroll
    for (int e = 0; e < 4; ++e) {
      if (t + e < NT) {
        rD[e] = Cw[e];
        iD[e] = -Sw[e];
        if (mir) { rM[e] = Cw[e]; iM[e] = Sw[e]; }
      }
    }
  }
}

// ==================== radix-4 fallback (R14, proven 61.7 us) ====================

__global__ __launch_bounds__(256) void conv_w_split4(
    const float* __restrict__ wsin, const float* __restrict__ wcos,
    short* __restrict__ wc4, short* __restrict__ ws4) {
  const int row = blockIdx.x;
  const int n0 = threadIdx.x * 8;
  const int m0 = n0 >> 2;
  short2v c[4], s[4];
  if (row <= 256) {
    const float* pc = wcos + (size_t)row * NFFT + n0;
    const float* ps = wsin + (size_t)row * NFFT + n0;
    f32x4 c0 = *(const f32x4*)pc, c1 = *(const f32x4*)(pc + 4);
    f32x4 s0 = *(const f32x4*)ps, s1 = *(const f32x4*)(ps + 4);
#pragma unroll
    for (int r = 0; r < 4; ++r) {
      c[r][0] = cvt_bf16(c0[r]); c[r][1] = cvt_bf16(c1[r]);
      s[r][0] = cvt_bf16(s0[r]); s[r][1] = cvt_bf16(s1[r]);
    }
  } else {
#pragma unroll
    for (int r = 0; r < 4; ++r) { c[r][0] = 0; c[r][1] = 0; s[r][0] = 0; s[r][1] = 0; }
  }
  const size_t o = (size_t)row * KQ + m0;
#pragma unroll
  for (int r = 0; r < 4; ++r) {
    *(short2v*)&wc4[r * WSTR + o] = c[r];
    *(short2v*)&ws4[r * WSTR + o] = s[r];
  }
}

__global__ __launch_bounds__(256) void conv_fr_split4(const float* __restrict__ x,
                                                      short* __restrict__ fr4) {
  const int j = blockIdx.x;
  const int b = j / NTP;
  const int t = j - b * NTP;
  const int n0 = threadIdx.x * 8;
  const int m0 = n0 >> 2;
  short2v v[4];
  if (t < NT) {
    const float* xb = x + (size_t)b * XLEN;
    const int q0 = t * 512 + n0 - 1024;
    float f[8];
    if (q0 >= 0 && q0 + 7 < XLEN) {
      *(f32x4*)(f)     = *(const f32x4*)(xb + q0);
      *(f32x4*)(f + 4) = *(const f32x4*)(xb + q0 + 4);
    } else {
#pragma unroll
      for (int e = 0; e < 8; ++e) {
        int mm = q0 + e;
        mm = (mm < 0) ? -mm : mm;
        mm = (mm >= XLEN) ? (2 * XLEN - 2 - mm) : mm;
        f[e] = xb[mm];
      }
    }
#pragma unroll
    for (int r = 0; r < 4; ++r) { v[r][0] = cvt_bf16(f[r]); v[r][1] = cvt_bf16(f[4 + r]); }
  } else {
#pragma unroll
    for (int r = 0; r < 4; ++r) { v[r][0] = 0; v[r][1] = 0; }
  }
#pragma unroll
  for (int r = 0; r < 4; ++r)
    *(short2v*)&fr4[r * FSTR + (size_t)j * KQ + m0] = v[r];
}

__global__ __launch_bounds__(256, 3) void dft_gemm_split4(
    const short* __restrict__ wc4, const short* __restrict__ ws4,
    const short* __restrict__ fr4,
    short* __restrict__ pC4, short* __restrict__ pS4) {
  __shared__ short lds[16384];

  const int tid  = threadIdx.x;
  const int lane = tid & 63;
  const int wid  = tid >> 6;

  const int o   = blockIdx.x;
  const int xcd = o & 7;
  const int i   = o >> 3;
  const int wg  = ((xcd < 4) ? xcd * 83 : 332 + (xcd - 4) * 82) + i;
  const int side = wg / 165;
  const int w    = wg - side * 165;
  const int k0   = (w % 5) * 64;
  const int j0   = (w / 5) * 128;

  const short* Ac = wc4 + side * WSTR;
  const short* As = ws4 + side * WSTR;
  const short* Bf = fr4 + side * FSTR;
  short* pC = pC4 + side * PSTR;
  short* pS = pS4 + side * PSTR;

  const int wrow = (wid >> 1) * 32;
  const int wcol = (wid & 1) * 64;

  f32x4 accC[2][4], accS[2][4];
#pragma unroll
  for (int m = 0; m < 2; ++m)
#pragma unroll
    for (int n = 0; n < 4; ++n) { accC[m][n] = (f32x4)0.0f; accS[m][n] = (f32x4)0.0f; }

  const int fr_r = lane & 15;
  const int srow = lane >> 3;
  const int scol = ((lane & 7) ^ srow) * 8;

  auto stage = [&](int n0) {
#pragma unroll
    for (int i2 = 0; i2 < 8; ++i2) {
      const int q = wid * 8 + i2;
      const short* src;
      int dst;
      if (q < 8) {
        src = Ac + (size_t)(k0 + q * 8 + srow) * KQ + n0 + scol;
        dst = q * 512;
      } else if (q < 16) {
        src = As + (size_t)(k0 + (q - 8) * 8 + srow) * KQ + n0 + scol;
        dst = 4096 + (q - 8) * 512;
      } else {
        src = Bf + (size_t)(j0 + (q - 16) * 8 + srow) * KQ + n0 + scol;
        dst = 8192 + (q - 16) * 512;
      }
      gload16(src, &lds[dst]);
    }
  };

  for (int ts = 0; ts < 8; ++ts) {
    if (ts) __syncthreads();
    stage(ts * 64);
    __syncthreads();
#pragma unroll
    for (int ks = 0; ks < 2; ++ks) {
      const int cc = ks * 4 + (lane >> 4);
      short8 aC[2], aS[2], bF[4];
#pragma unroll
      for (int m = 0; m < 2; ++m) {
        const int r = wrow + m * 16 + fr_r;
        const int off = (r << 6) + ((cc ^ (r & 7)) << 3);
        aC[m] = *(const short8*)&lds[off];
        aS[m] = *(const short8*)&lds[4096 + off];
      }
#pragma unroll
      for (int n = 0; n < 4; ++n) {
        const int r = wcol + n * 16 + fr_r;
        const int off = (r << 6) + ((cc ^ (r & 7)) << 3);
        bF[n] = *(const short8*)&lds[8192 + off];
      }
#pragma unroll
      for (int m = 0; m < 2; ++m)
#pragma unroll
        for (int n = 0; n < 4; ++n) {
          accC[m][n] = __builtin_amdgcn_mfma_f32_16x16x32_bf16(aC[m], bF[n], accC[m][n], 0, 0, 0);
          accS[m][n] = __builtin_amdgcn_mfma_f32_16x16x32_bf16(aS[m], bF[n], accS[m][n], 0, 0, 0);
        }
    }
  }

#pragma unroll
  for (int m = 0; m < 2; ++m) {
    const int row = k0 + wrow + m * 16 + (lane >> 4) * 4;
#pragma unroll
    for (int n = 0; n < 4; ++n) {
      const int col = j0 + wcol + n * 16 + (lane & 15);
      const size_t base = (size_t)row * NCOL + col;
#pragma unroll
      for (int r = 0; r < 4; ++r) {
        pC[base + (size_t)r * NCOL] = cvt_bf16(accC[m][n][r]);
        pS[base + (size_t)r * NCOL] = cvt_bf16(accS[m][n][r]);
      }
    }
  }
}

__global__ __launch_bounds__(256) void combine4_kernel(
    const short* __restrict__ pC4, const short* __restrict__ pS4,
    float* __restrict__ outR, float* __restrict__ outI) {
  const int k  = blockIdx.y;
  const int jq = blockIdx.x * 256 + threadIdx.x;
  if (jq >= NCOL / 4) return;
  const int j = jq * 4;
  const int b = j / NTP;
  const int t = j - b * NTP;
  const size_t pb = (size_t)k * NCOL + j;
  f32x4 C[4], S[4];
#pragma unroll
  for (int r = 0; r < 4; ++r) {
    C[r] = bf4_to_f32(*(const short4v*)&pC4[r * PSTR + pb]);
    S[r] = bf4_to_f32(*(const short4v*)&pS4[r * PSTR + pb]);
  }
  const f32x4 CA = C[0] + C[2], CB = C[1] + C[3];
  const f32x4 CmA = C[0] - C[2], CmB = C[1] - C[3];
  const f32x4 SA = S[0] + S[2], SB = S[1] + S[3];
  const f32x4 SmA = S[0] - S[2], SmB = S[1] - S[3];

  f32x4 Cw[4], Sw[4];
  Cw[0] = CA + CB;   Sw[0] = SA + SB;
  Cw[1] = CmA - SmB; Sw[1] = SmA + CmB;
  Cw[2] = CA - CB;   Sw[2] = SA - SB;
  Cw[3] = CmA + SmB; Sw[3] = SmA - CmB;

  const size_t ob = (size_t)b * OUTKT + t;
  const bool mir = (k >= 1) && (k <= 255);
#pragma unroll
  for (int jj = 0; jj < 4; ++jj) {
    const int rowD = 512 * jj + k;
    float* rD = outR + ob + (size_t)rowD * NT;
    float* iD = outI + ob + (size_t)rowD * NT;
    const int rowM = 512 * (4 - jj) - k;
    float* rM = outR + ob + (size_t)rowM * NT;
    float* iM = outI + ob + (size_t)rowM * NT;
#pragma unroll
    for (int e = 0; e < 4; ++e) {
      if (t + e < NT) {
        rD[e] = Cw[jj][e];
        iD[e] = -Sw[jj][e];
        if (mir) { rM[e] = Cw[jj][e]; iM[e] = Sw[jj][e]; }
      }
    }
  }
}

// ==================== host ====================

extern "C" void kernel_launch(void* const* d_in, const int* in_sizes, int n_in,
                              void* d_out, int out_size, void* d_ws, size_t ws_size,
                              hipStream_t stream) {
  const float* x    = (const float*)d_in[0];
  const float* wsin = (const float*)d_in[1];
  const float* wcos = (const float*)d_in[2];
  float* outR = (float*)d_out;
  float* outI = outR + (size_t)NB * OUTKT;

  const size_t need8 = (16 * WSTR8 + 8 * FSTR8 + 16 * PSTR8) * sizeof(short);  // ~44.8 MB

  if (ws_size >= need8) {
    short* wc8 = (short*)d_ws;                    // [8][192][256]
    short* ws8 = wc8 + 8 * WSTR8;                 // [8][192][256]
    short* fr8 = ws8 + 8 * WSTR8;                 // [8][4224][256]
    short* pC8 = fr8 + 8 * FSTR8;                 // [8][192][4224] bf16
    short* pS8 = pC8 + 8 * PSTR8;                 // [8][192][4224] bf16

    conv_w_split8<<<NKC8, 256, 0, stream>>>(wsin, wcos, wc8, ws8);
    conv_fr_split8<<<NCOL, 256, 0, stream>>>(x, fr8);
    dft_gemm_split8<<<792, 256, 0, stream>>>(wc8, ws8, fr8, pC8, pS8);
    combine8_kernel<<<dim3(5, 129), 256, 0, stream>>>(pC8, pS8, outR, outI);
  } else {
    // radix-4 fallback (R14, ~41.6 MB)
    short* wc4 = (short*)d_ws;
    short* ws4 = wc4 + 4 * WSTR;
    short* fr4 = ws4 + 4 * WSTR;
    short* pC4 = fr4 + 4 * FSTR;
    short* pS4 = pC4 + 4 * PSTR;

    conv_w_split4<<<NKC4, 256, 0, stream>>>(wsin, wcos, wc4, ws4);
    conv_fr_split4<<<NCOL, 256, 0, stream>>>(x, fr4);
    dft_gemm_split4<<<660, 256, 0, stream>>>(wc4, ws4, fr4, pC4, pS4);
    combine4_kernel<<<dim3(5, 257), 256, 0, stream>>>(pC4, pS4, outR, outI);
  }
}

// Round 16
// 57.085 us; speedup vs baseline: 1.1215x; 1.1215x over previous
//
#include <hip/hip_runtime.h>
#include <hip/hip_bf16.h>
#include <stdint.h>

#define XLEN   262144
#define NT     513
#define NTP    528               // padded frames per batch (8*528 = 4224)
#define NB     8
#define NCOL   (NB * NTP)        // 4224 fused columns
#define NKC4   320               // padded computed k rows (valid 0..256), 5 tiles
#define KQ     512               // quarter transform length (radix-4)
#define NK     1088              // fallback path: direct rows
#define NFFT   2048
#define OUTKT  (2048 * NT)
#define WSTR   ((size_t)NKC4 * KQ)   // 163,840 shorts per weight mat
#define FSTR   ((size_t)NCOL * KQ)   // 2,162,688 shorts per frame mat
#define PSTR   ((size_t)NKC4 * NCOL) // 1,351,680 elements per partial (bf16)

typedef __attribute__((ext_vector_type(8))) short short8;
typedef __attribute__((ext_vector_type(4))) short short4v;
typedef __attribute__((ext_vector_type(2))) short short2v;
typedef __attribute__((ext_vector_type(4))) float f32x4;

__device__ __forceinline__ short cvt_bf16(float f) {
  return __builtin_bit_cast(short, (__bf16)f);
}

__device__ __forceinline__ f32x4 bf4_to_f32(short4v v) {
  f32x4 o;
#pragma unroll
  for (int e = 0; e < 4; ++e) {
    uint32_t u = ((uint32_t)(uint16_t)v[e]) << 16;
    o[e] = __builtin_bit_cast(float, u);
  }
  return o;
}

__device__ __forceinline__ void gload16(const short* g, const short* l) {
  __builtin_amdgcn_global_load_lds(
      (const __attribute__((address_space(1))) void*)g,
      (__attribute__((address_space(3))) void*)l, 16, 0, 0);
}

// ==================== radix-4 split path (R14-proven) ====================

// ---- fused prep: blocks [0,NKC4) split weights; [NKC4, NKC4+NCOL) split frames.
// Weight path: rows 0..256 by n mod 4 -> 8 bf16 mats [320][512].
// Frame path: reflect-padded frames by n mod 4 -> 4 bf16 mats [4224][512].
__global__ __launch_bounds__(256) void conv_prep4(
    const float* __restrict__ x,
    const float* __restrict__ wsin, const float* __restrict__ wcos,
    short* __restrict__ wc4, short* __restrict__ ws4,
    short* __restrict__ fr4) {
  const int n0 = threadIdx.x * 8;
  const int m0 = n0 >> 2;
  if (blockIdx.x < NKC4) {
    const int row = blockIdx.x;           // 0..319
    short2v c[4], s[4];
    if (row <= 256) {
      const float* pc = wcos + (size_t)row * NFFT + n0;
      const float* ps = wsin + (size_t)row * NFFT + n0;
      f32x4 c0 = *(const f32x4*)pc, c1 = *(const f32x4*)(pc + 4);
      f32x4 s0 = *(const f32x4*)ps, s1 = *(const f32x4*)(ps + 4);
#pragma unroll
      for (int r = 0; r < 4; ++r) {
        c[r][0] = cvt_bf16(c0[r]); c[r][1] = cvt_bf16(c1[r]);
        s[r][0] = cvt_bf16(s0[r]); s[r][1] = cvt_bf16(s1[r]);
      }
    } else {
#pragma unroll
      for (int r = 0; r < 4; ++r) { c[r][0] = 0; c[r][1] = 0; s[r][0] = 0; s[r][1] = 0; }
    }
    const size_t o = (size_t)row * KQ + m0;
#pragma unroll
    for (int r = 0; r < 4; ++r) {
      *(short2v*)&wc4[r * WSTR + o] = c[r];
      *(short2v*)&ws4[r * WSTR + o] = s[r];
    }
  } else {
    const int j = blockIdx.x - NKC4;      // 0..4223
    const int b = j / NTP;
    const int t = j - b * NTP;
    short2v v[4];
    if (t < NT) {
      const float* xb = x + (size_t)b * XLEN;
      const int q0 = t * 512 + n0 - 1024;
      float f[8];
      if (q0 >= 0 && q0 + 7 < XLEN) {
        *(f32x4*)(f)     = *(const f32x4*)(xb + q0);
        *(f32x4*)(f + 4) = *(const f32x4*)(xb + q0 + 4);
      } else {
#pragma unroll
        for (int e = 0; e < 8; ++e) {
          int mm = q0 + e;
          mm = (mm < 0) ? -mm : mm;
          mm = (mm >= XLEN) ? (2 * XLEN - 2 - mm) : mm;
          f[e] = xb[mm];
        }
      }
#pragma unroll
      for (int r = 0; r < 4; ++r) { v[r][0] = cvt_bf16(f[r]); v[r][1] = cvt_bf16(f[4 + r]); }
    } else {
#pragma unroll
      for (int r = 0; r < 4; ++r) { v[r][0] = 0; v[r][1] = 0; }
    }
#pragma unroll
    for (int r = 0; r < 4; ++r)
      *(short2v*)&fr4[r * FSTR + (size_t)j * KQ + m0] = v[r];
  }
}

// ---- split GEMM: R11-proven structure, K=512, one residue side per block ----
// BM=64, BN=128, BK=64; 4 waves 2x2, each 32x64 per matrix; per substep
// 8 ds_read_b128 : 16 MFMA. LDS single 32 KiB [A_c 64x64 | A_s 64x64 | B 128x64],
// (row&7) 16B-chunk XOR swizzle on global source + ds_read (rule #21).
// Partials written as bf16 (halves partial traffic; error budget audited R14).
__global__ __launch_bounds__(256, 3) void dft_gemm_split4(
    const short* __restrict__ wc4, const short* __restrict__ ws4,
    const short* __restrict__ fr4,
    short* __restrict__ pC4, short* __restrict__ pS4) {
  __shared__ short lds[16384];  // 32 KiB

  const int tid  = threadIdx.x;
  const int lane = tid & 63;
  const int wid  = tid >> 6;

  // bijective XCD swizzle (m204): nwg=660, q=82, r=4.
  const int o   = blockIdx.x;
  const int xcd = o & 7;
  const int i   = o >> 3;
  const int wg  = ((xcd < 4) ? xcd * 83 : 332 + (xcd - 4) * 82) + i;
  const int side = wg / 165;        // residue r = 0..3
  const int w    = wg - side * 165;
  const int k0   = (w % 5) * 64;
  const int j0   = (w / 5) * 128;

  const short* Ac = wc4 + side * WSTR;
  const short* As = ws4 + side * WSTR;
  const short* Bf = fr4 + side * FSTR;
  short* pC = pC4 + side * PSTR;
  short* pS = pS4 + side * PSTR;

  const int wrow = (wid >> 1) * 32;
  const int wcol = (wid & 1) * 64;

  f32x4 accC[2][4], accS[2][4];
#pragma unroll
  for (int m = 0; m < 2; ++m)
#pragma unroll
    for (int n = 0; n < 4; ++n) { accC[m][n] = (f32x4)0.0f; accS[m][n] = (f32x4)0.0f; }

  const int fr_r = lane & 15;
  const int srow = lane >> 3;
  const int scol = ((lane & 7) ^ srow) * 8;

  // buffer = 32 chunks of (8 rows x 64 shorts); 8 per wave
  auto stage = [&](int n0) {
#pragma unroll
    for (int i2 = 0; i2 < 8; ++i2) {
      const int q = wid * 8 + i2;  // wave-uniform
      const short* src;
      int dst;
      if (q < 8) {
        src = Ac + (size_t)(k0 + q * 8 + srow) * KQ + n0 + scol;
        dst = q * 512;
      } else if (q < 16) {
        src = As + (size_t)(k0 + (q - 8) * 8 + srow) * KQ + n0 + scol;
        dst = 4096 + (q - 8) * 512;
      } else {
        src = Bf + (size_t)(j0 + (q - 16) * 8 + srow) * KQ + n0 + scol;
        dst = 8192 + (q - 16) * 512;
      }
      gload16(src, &lds[dst]);
    }
  };

  for (int ts = 0; ts < 8; ++ts) {
    if (ts) __syncthreads();
    stage(ts * 64);
    __syncthreads();
#pragma unroll
    for (int ks = 0; ks < 2; ++ks) {
      const int cc = ks * 4 + (lane >> 4);
      short8 aC[2], aS[2], bF[4];
#pragma unroll
      for (int m = 0; m < 2; ++m) {
        const int r = wrow + m * 16 + fr_r;
        const int off = (r << 6) + ((cc ^ (r & 7)) << 3);
        aC[m] = *(const short8*)&lds[off];
        aS[m] = *(const short8*)&lds[4096 + off];
      }
#pragma unroll
      for (int n = 0; n < 4; ++n) {
        const int r = wcol + n * 16 + fr_r;
        const int off = (r << 6) + ((cc ^ (r & 7)) << 3);
        bF[n] = *(const short8*)&lds[8192 + off];
      }
#pragma unroll
      for (int m = 0; m < 2; ++m)
#pragma unroll
        for (int n = 0; n < 4; ++n) {
          accC[m][n] = __builtin_amdgcn_mfma_f32_16x16x32_bf16(aC[m], bF[n], accC[m][n], 0, 0, 0);
          accS[m][n] = __builtin_amdgcn_mfma_f32_16x16x32_bf16(aS[m], bF[n], accS[m][n], 0, 0, 0);
        }
    }
  }

  // epilogue: bf16 partial write (16 consecutive lanes -> 32B contiguous)
#pragma unroll
  for (int m = 0; m < 2; ++m) {
    const int row = k0 + wrow + m * 16 + (lane >> 4) * 4;
#pragma unroll
    for (int n = 0; n < 4; ++n) {
      const int col = j0 + wcol + n * 16 + (lane & 15);
      const size_t base = (size_t)row * NCOL + col;
#pragma unroll
      for (int r = 0; r < 4; ++r) {
        pC[base + (size_t)r * NCOL] = cvt_bf16(accC[m][n][r]);
        pS[base + (size_t)r * NCOL] = cvt_bf16(accS[m][n][r]);
      }
    }
  }
}

// ---- combine: radix-4 butterfly + Hermitian mirrors (bf16 partials in) ----
// k in [0,256]. Direct rows d = 512*jj + k (always);
// mirror rows 2048 - d = 512*(4-jj) - k only for 1<=k<=255 (conj: outI flips).
// outR[row]=C_row, outI[row]=-S_row; mirrors: outR=C, outI=+S.
__global__ __launch_bounds__(256) void combine4_kernel(
    const short* __restrict__ pC4, const short* __restrict__ pS4,
    float* __restrict__ outR, float* __restrict__ outI) {
  const int k  = blockIdx.y;                       // 0..256
  const int jq = blockIdx.x * 256 + threadIdx.x;   // quad index
  if (jq >= NCOL / 4) return;
  const int j = jq * 4;
  const int b = j / NTP;
  const int t = j - b * NTP;                       // NTP%4==0 -> same b for all 4
  const size_t pb = (size_t)k * NCOL + j;
  f32x4 C[4], S[4];
#pragma unroll
  for (int r = 0; r < 4; ++r) {
    C[r] = bf4_to_f32(*(const short4v*)&pC4[r * PSTR + pb]);
    S[r] = bf4_to_f32(*(const short4v*)&pS4[r * PSTR + pb]);
  }
  const f32x4 CA = C[0] + C[2], CB = C[1] + C[3];
  const f32x4 CmA = C[0] - C[2], CmB = C[1] - C[3];
  const f32x4 SA = S[0] + S[2], SB = S[1] + S[3];
  const f32x4 SmA = S[0] - S[2], SmB = S[1] - S[3];

  f32x4 Cw[4], Sw[4];
  Cw[0] = CA + CB;   Sw[0] = SA + SB;    // row k
  Cw[1] = CmA - SmB; Sw[1] = SmA + CmB;  // row 512+k
  Cw[2] = CA - CB;   Sw[2] = SA - SB;    // row 1024+k
  Cw[3] = CmA + SmB; Sw[3] = SmA - CmB;  // row 1536+k

  const size_t ob = (size_t)b * OUTKT + t;
  const bool mir = (k >= 1) && (k <= 255);
#pragma unroll
  for (int jj = 0; jj < 4; ++jj) {
    const int rowD = 512 * jj + k;
    float* rD = outR + ob + (size_t)rowD * NT;
    float* iD = outI + ob + (size_t)rowD * NT;
    const int rowM = 512 * (4 - jj) - k;  // 2048-d: 2048-k,1536-k,1024-k,512-k
    float* rM = outR + ob + (size_t)rowM * NT;
    float* iM = outI + ob + (size_t)rowM * NT;
#pragma unroll
    for (int e = 0; e < 4; ++e) {
      if (t + e < NT) {
        rD[e] = Cw[jj][e];
        iD[e] = -Sw[jj][e];
        if (mir) { rM[e] = Cw[jj][e]; iM[e] = Sw[jj][e]; }
      }
    }
  }
}

// ==================== fallback: R4 full-K path (proven) ====================

__global__ __launch_bounds__(256) void conv_w_kernel(const float* __restrict__ wsin,
                                                     const float* __restrict__ wcos,
                                                     short* __restrict__ wc,
                                                     short* __restrict__ ws) {
  const int row = blockIdx.x;
  const int c = threadIdx.x * 8;
  const float* src = (blockIdx.y ? wsin : wcos) + (size_t)row * NFFT + c;
  short* dst = (blockIdx.y ? ws : wc) + (size_t)row * NFFT + c;
  f32x4 a = *(const f32x4*)src;
  f32x4 b = *(const f32x4*)(src + 4);
  short8 o;
#pragma unroll
  for (int j = 0; j < 4; ++j) { o[j] = cvt_bf16(a[j]); o[4 + j] = cvt_bf16(b[j]); }
  *(short8*)dst = o;
}

__global__ __launch_bounds__(256) void conv_frames_kernel(const float* __restrict__ x,
                                                          short* __restrict__ fr) {
  const int j = blockIdx.x;
  const int b = j / NTP;
  const int t = j - b * NTP;
  const int c = threadIdx.x * 8;
  short8 o;
  if (t >= NT) {
#pragma unroll
    for (int k = 0; k < 8; ++k) o[k] = 0;
  } else {
    const float* xb = x + (size_t)b * XLEN;
    const int base = t * 512 + c - 1024;
    float v[8];
    if (base >= 0 && base + 7 < XLEN) {
      *(f32x4*)(v)     = *(const f32x4*)(xb + base);
      *(f32x4*)(v + 4) = *(const f32x4*)(xb + base + 4);
    } else {
#pragma unroll
      for (int k = 0; k < 8; ++k) {
        int m = base + k;
        m = (m < 0) ? -m : m;
        m = (m >= XLEN) ? (2 * XLEN - 2 - m) : m;
        v[k] = xb[m];
      }
    }
#pragma unroll
    for (int k = 0; k < 8; ++k) o[k] = cvt_bf16(v[k]);
  }
  *(short8*)&fr[(size_t)j * NFFT + c] = o;
}

__global__ __launch_bounds__(256, 3) void dft_gemm_r4(
    const short* __restrict__ wc_bf,
    const short* __restrict__ ws_bf,
    const short* __restrict__ fr_bf,
    float* __restrict__ outR,
    float* __restrict__ outI) {
  __shared__ short lds[16384];

  const int tid  = threadIdx.x;
  const int lane = tid & 63;
  const int wid  = tid >> 6;

  const int o   = blockIdx.x;
  const int xcd = o & 7;
  const int wg  = ((xcd < 1) ? xcd * 71 : 71 + (xcd - 1) * 70) + (o >> 3);
  const int k0  = (wg % 17) * 64;
  const int j0  = (wg / 17) * 128;

  const int wrow = (wid >> 1) * 32;
  const int wcol = (wid & 1) * 64;

  f32x4 accR[2][4], accI[2][4];
#pragma unroll
  for (int m = 0; m < 2; ++m)
#pragma unroll
    for (int n = 0; n < 4; ++n) { accR[m][n] = (f32x4)0.0f; accI[m][n] = (f32x4)0.0f; }

  const int fr_r = lane & 15;
  const int srow = lane >> 3;
  const int scol = ((lane & 7) ^ srow) * 8;

  auto stage = [&](int n0) {
#pragma unroll
    for (int i = 0; i < 8; ++i) {
      const int q = wid * 8 + i;
      const short* src;
      int dst;
      if (q < 8) {
        src = wc_bf + (size_t)(k0 + q * 8 + srow) * NFFT + n0 + scol;
        dst = q * 512;
      } else if (q < 16) {
        src = ws_bf + (size_t)(k0 + (q - 8) * 8 + srow) * NFFT + n0 + scol;
        dst = 4096 + (q - 8) * 512;
      } else {
        src = fr_bf + (size_t)(j0 + (q - 16) * 8 + srow) * NFFT + n0 + scol;
        dst = 8192 + (q - 16) * 512;
      }
      gload16(src, &lds[dst]);
    }
  };

  for (int t = 0; t < 32; ++t) {
    if (t) __syncthreads();
    stage(t * 64);
    __syncthreads();
#pragma unroll
    for (int ks = 0; ks < 2; ++ks) {
      const int cc = ks * 4 + (lane >> 4);
      short8 a_c[2], a_s[2], b_f[4];
#pragma unroll
      for (int m = 0; m < 2; ++m) {
        const int r = wrow + m * 16 + fr_r;
        const int off = (r << 6) + ((cc ^ (r & 7)) << 3);
        a_c[m] = *(const short8*)&lds[off];
        a_s[m] = *(const short8*)&lds[4096 + off];
      }
#pragma unroll
      for (int n = 0; n < 4; ++n) {
        const int r = wcol + n * 16 + fr_r;
        const int off = (r << 6) + ((cc ^ (r & 7)) << 3);
        b_f[n] = *(const short8*)&lds[8192 + off];
      }
#pragma unroll
      for (int m = 0; m < 2; ++m)
#pragma unroll
        for (int n = 0; n < 4; ++n) {
          accR[m][n] = __builtin_amdgcn_mfma_f32_16x16x32_bf16(a_c[m], b_f[n], accR[m][n], 0, 0, 0);
          accI[m][n] = __builtin_amdgcn_mfma_f32_16x16x32_bf16(a_s[m], b_f[n], accI[m][n], 0, 0, 0);
        }
    }
  }

#pragma unroll
  for (int m = 0; m < 2; ++m) {
    const int k = k0 + wrow + m * 16 + (lane >> 4) * 4;
#pragma unroll
    for (int n = 0; n < 4; ++n) {
      const int j = j0 + wcol + n * 16 + (lane & 15);
      const int b = j / NTP;
      const int t = j - b * NTP;
      if (t < NT) {
        const size_t base = (size_t)b * OUTKT + (size_t)k * NT + t;
#pragma unroll
        for (int r = 0; r < 4; ++r) {
          const int kk = k + r;
          const float vr = accR[m][n][r];
          const float vi = accI[m][n][r];
          outR[base + (size_t)r * NT] = vr;
          outI[base + (size_t)r * NT] = -vi;
          if (kk >= 1 && kk <= 960) {
            const size_t mb = (size_t)b * OUTKT + (size_t)(2048 - kk) * NT + t;
            outR[mb] = vr;
            outI[mb] = vi;
          }
        }
      }
    }
  }
}

// ==================== host ====================

extern "C" void kernel_launch(void* const* d_in, const int* in_sizes, int n_in,
                              void* d_out, int out_size, void* d_ws, size_t ws_size,
                              hipStream_t stream) {
  const float* x    = (const float*)d_in[0];
  const float* wsin = (const float*)d_in[1];
  const float* wcos = (const float*)d_in[2];
  float* outR = (float*)d_out;
  float* outI = outR + (size_t)NB * OUTKT;

  // radix-4 workspace: 8 weight mats + 4 frame mats + 8 bf16 partials (~41.6 MB)
  const size_t need4 = (8 * WSTR + 4 * FSTR + 8 * PSTR) * sizeof(short);

  if (ws_size >= need4) {
    short* wc4 = (short*)d_ws;                    // [4][320][512]
    short* ws4 = wc4 + 4 * WSTR;                  // [4][320][512]
    short* fr4 = ws4 + 4 * WSTR;                  // [4][4224][512]
    short* pC4 = fr4 + 4 * FSTR;                  // [4][320][4224] bf16
    short* pS4 = pC4 + 4 * PSTR;                  // [4][320][4224] bf16

    conv_prep4<<<NKC4 + NCOL, 256, 0, stream>>>(x, wsin, wcos, wc4, ws4, fr4);
    dft_gemm_split4<<<660, 256, 0, stream>>>(wc4, ws4, fr4, pC4, pS4);
    combine4_kernel<<<dim3(5, 257), 256, 0, stream>>>(pC4, pS4, outR, outI);
  } else {
    // R4 full-K fallback (needs ~26.2 MB)
    short* wc_bf = (short*)d_ws;
    short* ws_bf = wc_bf + (size_t)NK * NFFT;
    short* fr_bf = ws_bf + (size_t)NK * NFFT;
    conv_w_kernel<<<dim3(NK, 2), 256, 0, stream>>>(wsin, wcos, wc_bf, ws_bf);
    conv_frames_kernel<<<NCOL, 256, 0, stream>>>(x, fr_bf);
    dft_gemm_r4<<<561, 256, 0, stream>>>(wc_bf, ws_bf, fr_bf, outR, outI);
  }
}